// Round 1
// baseline (5514.453 us; speedup 1.0000x reference)
//
#include <hip/hip_runtime.h>
#include <hip/hip_bf16.h>

// Layout notes:
//  a, t : [B=64][C=32][H=64][Wp=128][S=2] bf16, (r,i) interleaved, w>=121 zeroed
//  csum : [B=64][C=32][H=64][Wp=128] fp32  (accumulates (w00*relu_r + w01*relu_i)/3 per layer)
//  ws total = 64MB + 64MB + 128MB = 256MiB

__device__ __forceinline__ float bf2f(__hip_bfloat16 v) { return __bfloat162float(v); }

// ---------------------------------------------------------------------------
// Kernel 1: fused STFT + QK^T + sigmoid + A, one block per (b,n).
// Hermitian symmetry: compute f=0..32, mirror f=33..63.
// ---------------------------------------------------------------------------
__global__ __launch_bounds__(512) void stft_qk_a_k(const float* __restrict__ x,
                                                   __hip_bfloat162* __restrict__ a) {
  const int bid = blockIdx.x;
  const int b = bid >> 5, n = bid & 31;
  __shared__ float s_sr[64][121];
  __shared__ float s_si[64][121];
  __shared__ float s_un[33 * 64 * 2 + 544];   // {wcos,wsin,xp} then reused as {Qr,Qi}
  float* wc  = s_un;
  float* ws2 = s_un + 33 * 64;
  float* xp  = s_un + 33 * 64 * 2;
  float* Qr  = s_un;
  float* Qi  = s_un + 33 * 64;
  const int tid = threadIdx.x;

  // reflect-padded signal (pad=32, torch center=True reflect)
  for (int i = tid; i < 544; i += 512) {
    int p = i - 32;
    if (p < 0) p = -p;
    if (p >= 480) p = 958 - p;           // 2*479 - p
    xp[i] = x[(b * 480 + p) * 32 + n];
  }
  // windowed DFT tables, f=0..32; exact integer phase mod 64 for precision
  const float PI32 = 0.0981747704246810387f;  // pi/32
  for (int i = tid; i < 33 * 64; i += 512) {
    int f = i >> 6, t = i & 63;
    float win = 0.5f * (1.0f - __cosf(PI32 * (float)t));  // periodic hann
    int m = (f * t) & 63;
    float sv, cv;
    __sincosf(PI32 * (float)m, &sv, &cv);
    wc[i]  =  win * cv * 0.125f;   // 1/sqrt(64)
    ws2[i] = -win * sv * 0.125f;
  }
  __syncthreads();

  // DFT: s[f][k], f<=32, mirrored into f=33..63
  for (int id = tid; id < 33 * 121; id += 512) {
    int f = id / 121, k = id - f * 121;
    const float* xk  = xp + k * 4;
    const float* wcf = wc + (f << 6);
    const float* wsf = ws2 + (f << 6);
    float ar = 0.f, ai = 0.f;
#pragma unroll
    for (int t = 0; t < 64; ++t) {
      float v = xk[t];
      ar = fmaf(v, wcf[t], ar);
      ai = fmaf(v, wsf[t], ai);
    }
    s_sr[f][k] = ar; s_si[f][k] = ai;
    if (f >= 1 && f <= 31) { s_sr[64 - f][k] = ar; s_si[64 - f][k] = -ai; }
  }
  __syncthreads();

  // QK^T (rows f<=32 only) + sigmoid
  for (int id = tid; id < 33 * 64; id += 512) {
    int f = id >> 6, g = id & 63;
    float qr = 0.f, qi = 0.f;
    for (int k = 0; k < 121; ++k) {
      float ar = s_sr[f][k], ai = s_si[f][k];
      float br = s_sr[g][k], bi = s_si[g][k];
      qr += ar * br - ai * bi;
      qi += ar * bi + ai * br;
    }
    Qr[id] = 1.f / (1.f + __expf(-qr));
    Qi[id] = 1.f / (1.f + __expf(-qi));
  }
  __syncthreads();

  // A = sigmoid(QK) @ S   (rows f<=32, mirror the rest: a[64-f] = conj(a[f]))
  for (int id = tid; id < 33 * 121; id += 512) {
    int f = id / 121, k = id - f * 121;
    const float* qrf = Qr + (f << 6);
    const float* qif = Qi + (f << 6);
    float ar = 0.f, ai = 0.f;
#pragma unroll 8
    for (int g = 0; g < 64; ++g) {
      float qr = qrf[g], qi = qif[g];
      float sr = s_sr[g][k], si = s_si[g][k];
      ar += qr * sr - qi * si;
      ai += qr * si + qi * sr;
    }
    int base = ((b * 32 + n) * 64 + f) * 128 + k;
    __hip_bfloat162 v;
    v.x = __float2bfloat16(ar); v.y = __float2bfloat16(ai);
    a[base] = v;
    if (f >= 1 && f <= 31) {
      int base2 = ((b * 32 + n) * 64 + (64 - f)) * 128 + k;
      __hip_bfloat162 v2;
      v2.x = v.x; v2.y = __float2bfloat16(-ai);
      a[base2] = v2;
    }
  }
  // zero the W-pad columns (121..127) so convs get correct zero padding
  for (int id = tid; id < 64 * 7; id += 512) {
    int f = id / 7, k = 121 + (id - f * 7);
    int base = ((b * 32 + n) * 64 + f) * 128 + k;
    __hip_bfloat162 z;
    z.x = __float2bfloat16(0.f); z.y = __float2bfloat16(0.f);
    a[base] = z;
  }
}

// ---------------------------------------------------------------------------
// Kernel 2: 1x1 complex conv + csum init. Block = (b,h).
// csum = (w00*relu(r0) + w01*relu(i0))/3
// ---------------------------------------------------------------------------
__global__ __launch_bounds__(256) void conv0_k(const __hip_bfloat162* __restrict__ a,
    const float* __restrict__ w0r, const float* __restrict__ w0i,
    const float* __restrict__ b0r, const float* __restrict__ b0i,
    const float* __restrict__ wl0, float* __restrict__ csum) {
  const int b = blockIdx.x >> 6, h = blockIdx.x & 63;
  __shared__ uint4 sbuf[32 * 32];               // 32c x 128w pairs (16KB)
  __shared__ float swr[1024], swi[1024];
  const __hip_bfloat162* sin_ = reinterpret_cast<const __hip_bfloat162*>(sbuf);
  const int tid = threadIdx.x;
  const uint4* asrc = reinterpret_cast<const uint4*>(a);
  for (int i = tid; i < 32 * 32; i += 256) {
    int c = i >> 5, q = i & 31;
    sbuf[i] = asrc[((b * 32 + c) * 64 + h) * 32 + q];
  }
  for (int i = tid; i < 1024; i += 256) { swr[i] = w0r[i]; swi[i] = w0i[i]; }
  __syncthreads();

  const int o = tid >> 3, wg = tid & 7;
  float accr[16], acci[16];
#pragma unroll
  for (int t = 0; t < 16; ++t) { accr[t] = 0.f; acci[t] = 0.f; }
  for (int c = 0; c < 32; ++c) {
    float wr = swr[o * 32 + c], wi = swi[o * 32 + c];
    const __hip_bfloat162* row = sin_ + c * 128;
#pragma unroll
    for (int t = 0; t < 16; ++t) {
      __hip_bfloat162 v = row[wg + 8 * t];
      float xr = bf2f(v.x), xi = bf2f(v.y);
      accr[t] += xr * wr - xi * wi;
      acci[t] += xi * wr + xr * wi;
    }
  }
  float br_ = b0r[o] - b0i[o], bi_ = b0r[o] + b0i[o];
  float w00 = wl0[0], w01 = wl0[1];
  float* crow = csum + ((b * 32 + o) * 64 + h) * 128;
#pragma unroll
  for (int t = 0; t < 16; ++t) {
    int w = wg + 8 * t;
    if (w < 121) {
      float r0 = accr[t] + br_, i0 = acci[t] + bi_;
      crow[w] = (fmaxf(r0, 0.f) * w00 + fmaxf(i0, 0.f) * w01) * (1.f / 3.f);
    } else {
      crow[w] = 0.f;
    }
  }
}

// ---------------------------------------------------------------------------
// Kernel 3: dilated 3x3 complex conv. Block = (b,h); stages rows h-d,h,h+d.
// STORE_T: write bf16 t (with bias, no relu, pad zeroed)
// !STORE_T: csum += (w00*relu + w01*relu)/3
// ---------------------------------------------------------------------------
template <bool STORE_T>
__global__ __launch_bounds__(256) void conv3_k(const __hip_bfloat162* __restrict__ in,
    __hip_bfloat162* __restrict__ outt,
    const float* __restrict__ gwr, const float* __restrict__ gwi,
    const float* __restrict__ gbr, const float* __restrict__ gbi,
    const int d,
    const float* __restrict__ wl0, float* __restrict__ csum) {
  const int b = blockIdx.x >> 6, h = blockIdx.x & 63;
  __shared__ uint4 sbuf[3 * 32 * 32];           // 3 rows x 32c x 128w pairs (48KB)
  const __hip_bfloat162* sin_ = reinterpret_cast<const __hip_bfloat162*>(sbuf);
  const int tid = threadIdx.x;
  const uint4* isrc = reinterpret_cast<const uint4*>(in);
  for (int i = tid; i < 3 * 32 * 32; i += 256) {
    int r = i >> 10;
    int rem = i & 1023;
    int c = rem >> 5, q = rem & 31;
    int hh = h + (r - 1) * d;
    uint4 v = make_uint4(0u, 0u, 0u, 0u);
    if (hh >= 0 && hh < 64) v = isrc[((b * 32 + c) * 64 + hh) * 32 + q];
    sbuf[i] = v;
  }
  __syncthreads();

  const int o = tid >> 3, wg = tid & 7;
  float accr[16], acci[16];
#pragma unroll
  for (int t = 0; t < 16; ++t) { accr[t] = 0.f; acci[t] = 0.f; }

  for (int c = 0; c < 32; ++c) {
    float wr9[9], wi9[9];
#pragma unroll
    for (int q = 0; q < 9; ++q) {
      wr9[q] = gwr[(o * 32 + c) * 9 + q];
      wi9[q] = gwi[(o * 32 + c) * 9 + q];
    }
#pragma unroll
    for (int dy = 0; dy < 3; ++dy) {
      const __hip_bfloat162* row = sin_ + (dy * 32 + c) * 128;
#pragma unroll
      for (int dx = 0; dx < 3; ++dx) {
        float wr = wr9[dy * 3 + dx], wi = wi9[dy * 3 + dx];
        int off = (dx - 1) * d;
#pragma unroll
        for (int t = 0; t < 16; ++t) {
          int w = wg + 8 * t + off;
          if ((unsigned)w < 128u) {     // w>=121 reads zeroed pad; w<0 skipped (zero pad)
            __hip_bfloat162 v = row[w];
            float xr = bf2f(v.x), xi = bf2f(v.y);
            accr[t] += xr * wr - xi * wi;
            acci[t] += xi * wr + xr * wi;
          }
        }
      }
    }
  }

  float br_ = gbr[o] - gbi[o], bi_ = gbr[o] + gbi[o];
  if (STORE_T) {
    __hip_bfloat162* trow = outt + ((b * 32 + o) * 64 + h) * 128;
#pragma unroll
    for (int t = 0; t < 16; ++t) {
      int w = wg + 8 * t;
      __hip_bfloat162 v;
      if (w < 121) {
        v.x = __float2bfloat16(accr[t] + br_);
        v.y = __float2bfloat16(acci[t] + bi_);
      } else {
        v.x = __float2bfloat16(0.f);
        v.y = __float2bfloat16(0.f);
      }
      trow[w] = v;
    }
  } else {
    float w00 = wl0[0], w01 = wl0[1];
    float* crow = csum + ((b * 32 + o) * 64 + h) * 128;
#pragma unroll
    for (int t = 0; t < 16; ++t) {
      int w = wg + 8 * t;
      if (w < 121) {
        float r0 = accr[t] + br_, i0 = acci[t] + bi_;
        crow[w] += (fmaxf(r0, 0.f) * w00 + fmaxf(i0, 0.f) * w01) * (1.f / 3.f);
      }
    }
  }
}

// ---------------------------------------------------------------------------
// Kernel 4: epilogue. h[k] = mean_f(csum) + b_l0 ; y[t] = h @ w_l2[t,:] + b_l2
// Block = (b,n).
// ---------------------------------------------------------------------------
__global__ __launch_bounds__(256) void epi_k(const float* __restrict__ csum,
    const float* __restrict__ bl0, const float* __restrict__ wl2,
    const float* __restrict__ bl2, float* __restrict__ out) {
  const int b = blockIdx.x >> 5, n = blockIdx.x & 31;
  __shared__ float sh[121];
  const int tid = threadIdx.x;
  const float* base = csum + ((b * 32 + n) * 64) * 128;
  for (int k = tid; k < 121; k += 256) {
    float s = 0.f;
#pragma unroll 8
    for (int f = 0; f < 64; ++f) s += base[f * 128 + k];
    sh[k] = s * (1.f / 64.f) + bl0[0];
  }
  __syncthreads();
  for (int t = tid; t < 480; t += 256) {
    float acc = bl2[t];
    const float* wrow = wl2 + t * 121;
#pragma unroll 8
    for (int k = 0; k < 121; ++k) acc = fmaf(sh[k], wrow[k], acc);
    out[(b * 480 + t) * 32 + n] = acc;
  }
}

// ---------------------------------------------------------------------------
extern "C" void kernel_launch(void* const* d_in, const int* in_sizes, int n_in,
                              void* d_out, int out_size, void* d_ws, size_t ws_size,
                              hipStream_t stream) {
  const float* x   = (const float*)d_in[0];
  const float* w0r = (const float*)d_in[1];
  const float* w0i = (const float*)d_in[2];
  const float* b0r = (const float*)d_in[3];
  const float* b0i = (const float*)d_in[4];
  const float* W1r = (const float*)d_in[5];
  const float* W1i = (const float*)d_in[6];
  const float* B1r = (const float*)d_in[7];
  const float* B1i = (const float*)d_in[8];
  const float* W2r = (const float*)d_in[9];
  const float* W2i = (const float*)d_in[10];
  const float* B2r = (const float*)d_in[11];
  const float* B2i = (const float*)d_in[12];
  const float* wl0 = (const float*)d_in[13];
  const float* bl0 = (const float*)d_in[14];
  const float* wl2 = (const float*)d_in[15];
  const float* bl2 = (const float*)d_in[16];

  char* ws = (char*)d_ws;
  const size_t SZA = (size_t)64 * 32 * 64 * 128 * 4;  // 67,108,864 B (bf16 pairs)
  __hip_bfloat162* a = (__hip_bfloat162*)ws;
  __hip_bfloat162* t = (__hip_bfloat162*)(ws + SZA);
  float* csum = (float*)(ws + 2 * SZA);
  float* out = (float*)d_out;

  hipLaunchKernelGGL(stft_qk_a_k, dim3(2048), dim3(512), 0, stream, x, a);
  hipLaunchKernelGGL(conv0_k, dim3(4096), dim3(256), 0, stream,
                     a, w0r, w0i, b0r, b0i, wl0, csum);
  // pair k=1 (dilation 1)
  hipLaunchKernelGGL((conv3_k<true>),  dim3(4096), dim3(256), 0, stream,
                     a, t, W1r, W1i, B1r, B1i, 1, wl0, csum);
  hipLaunchKernelGGL((conv3_k<false>), dim3(4096), dim3(256), 0, stream,
                     t, t, W2r, W2i, B2r, B2i, 1, wl0, csum);
  // pair k=2 (dilation 2)
  hipLaunchKernelGGL((conv3_k<true>),  dim3(4096), dim3(256), 0, stream,
                     a, t, W1r + 9216, W1i + 9216, B1r + 32, B1i + 32, 2, wl0, csum);
  hipLaunchKernelGGL((conv3_k<false>), dim3(4096), dim3(256), 0, stream,
                     t, t, W2r + 9216, W2i + 9216, B2r + 32, B2i + 32, 2, wl0, csum);
  hipLaunchKernelGGL(epi_k, dim3(2048), dim3(256), 0, stream, csum, bl0, wl2, bl2, out);
}

// Round 3
// 1057.713 us; speedup vs baseline: 5.2136x; 5.2136x over previous
//
#include <hip/hip_runtime.h>
#include <hip/hip_bf16.h>

// ---------------------------------------------------------------------------
// Workspace layout (256 MiB):
//  [0,64MB)    : a_planar [b][cc64][f64][w128] bf16   (dead after transpose)
//                -- overlaid after transpose by: AF (weight fragments hi+lo,
//                   737KB @0) and BB (real-ified biases @ +4MB)
//  [64,128MB)  : a_nhwc   [b][h64][w128][cc64] bf16
//  [128,192MB) : t_nhwc   [b][h64][w128][cc64] bf16
//  [192,256MB) : csum     [b][n32][h64][w128]  fp32
//
// Real-ified complex conv: channels cc<32 = real, cc>=32 = imag.
// Wbig[o][cc]: o<32 (real out): [wr | -wi]; o>=32 (imag out): [wi | wr].
// bias_big[o<32] = br-bi ; bias_big[o>=32] = br+bi.
// Weights are split-precision: part0 = bf16(w), part1 = bf16(w - part0),
// so MFMA effective weight error ~2^-17 (round-2's bf16-weight absmax fail).
// AF layout: [conv5][tap9][part2][ks2][mt4][lane64][j8] bf16.
// ---------------------------------------------------------------------------

typedef __attribute__((ext_vector_type(8))) short bf16x8;
typedef __attribute__((ext_vector_type(4))) float f32x4;

__device__ __forceinline__ ushort f2bf(float v) {
  __hip_bfloat16 h = __float2bfloat16(v);
  return *reinterpret_cast<ushort*>(&h);
}
__device__ __forceinline__ float bf2f_raw(ushort u) {
  union { uint i; float f; } c; c.i = ((uint)u) << 16; return c.f;
}

// ---------------------------------------------------------------------------
// Kernel 1: fused STFT + QK^T + sigmoid + A, one block per (b,n).
// Hermitian symmetry: compute f=0..32, mirror f=33..63.
// Writes a_planar [b][cc][f][w] bf16 (cc=n real, cc=n+32 imag), pad zeroed.
// ---------------------------------------------------------------------------
__global__ __launch_bounds__(512) void stft_qk_a_k(const float* __restrict__ x,
                                                   __hip_bfloat16* __restrict__ ap) {
  const int bid = blockIdx.x;
  const int b = bid >> 5, n = bid & 31;
  __shared__ float s_sr[64][121];
  __shared__ float s_si[64][121];
  __shared__ float s_un[33 * 64 * 2 + 544];
  float* wc  = s_un;
  float* ws2 = s_un + 33 * 64;
  float* xp  = s_un + 33 * 64 * 2;
  float* Qr  = s_un;
  float* Qi  = s_un + 33 * 64;
  const int tid = threadIdx.x;

  for (int i = tid; i < 544; i += 512) {
    int p = i - 32;
    if (p < 0) p = -p;
    if (p >= 480) p = 958 - p;
    xp[i] = x[(b * 480 + p) * 32 + n];
  }
  const float PI32 = 0.0981747704246810387f;  // pi/32
  for (int i = tid; i < 33 * 64; i += 512) {
    int f = i >> 6, t = i & 63;
    float win = 0.5f * (1.0f - __cosf(PI32 * (float)t));
    int m = (f * t) & 63;
    float sv, cv;
    __sincosf(PI32 * (float)m, &sv, &cv);
    wc[i]  =  win * cv * 0.125f;
    ws2[i] = -win * sv * 0.125f;
  }
  __syncthreads();

  for (int id = tid; id < 33 * 121; id += 512) {
    int f = id / 121, k = id - f * 121;
    const float* xk  = xp + k * 4;
    const float* wcf = wc + (f << 6);
    const float* wsf = ws2 + (f << 6);
    float ar = 0.f, ai = 0.f;
#pragma unroll
    for (int t = 0; t < 64; ++t) {
      float v = xk[t];
      ar = fmaf(v, wcf[t], ar);
      ai = fmaf(v, wsf[t], ai);
    }
    s_sr[f][k] = ar; s_si[f][k] = ai;
    if (f >= 1 && f <= 31) { s_sr[64 - f][k] = ar; s_si[64 - f][k] = -ai; }
  }
  __syncthreads();

  for (int id = tid; id < 33 * 64; id += 512) {
    int f = id >> 6, g = id & 63;
    float qr = 0.f, qi = 0.f;
    for (int k = 0; k < 121; ++k) {
      float ar = s_sr[f][k], ai = s_si[f][k];
      float br = s_sr[g][k], bi = s_si[g][k];
      qr += ar * br - ai * bi;
      qi += ar * bi + ai * br;
    }
    Qr[id] = 1.f / (1.f + __expf(-qr));
    Qi[id] = 1.f / (1.f + __expf(-qi));
  }
  __syncthreads();

  // A = sigmoid(QK) @ S ; write planar bf16, mirrored rows
  for (int id = tid; id < 33 * 121; id += 512) {
    int f = id / 121, k = id - f * 121;
    const float* qrf = Qr + (f << 6);
    const float* qif = Qi + (f << 6);
    float ar = 0.f, ai = 0.f;
#pragma unroll 8
    for (int g = 0; g < 64; ++g) {
      float qr = qrf[g], qi = qif[g];
      float sr = s_sr[g][k], si = s_si[g][k];
      ar += qr * sr - qi * si;
      ai += qr * si + qi * sr;
    }
    ap[((b * 64 + n) * 64 + f) * 128 + k]      = __float2bfloat16(ar);
    ap[((b * 64 + n + 32) * 64 + f) * 128 + k] = __float2bfloat16(ai);
    if (f >= 1 && f <= 31) {
      int f2 = 64 - f;
      ap[((b * 64 + n) * 64 + f2) * 128 + k]      = __float2bfloat16(ar);
      ap[((b * 64 + n + 32) * 64 + f2) * 128 + k] = __float2bfloat16(-ai);
    }
  }
  // zero pad columns w in [121,128) for both planes
  for (int i = tid; i < 64 * 7; i += 512) {
    int f = i / 7, k = 121 + (i - (i / 7) * 7);
    ap[((b * 64 + n) * 64 + f) * 128 + k]      = __float2bfloat16(0.f);
    ap[((b * 64 + n + 32) * 64 + f) * 128 + k] = __float2bfloat16(0.f);
  }
}

// ---------------------------------------------------------------------------
// Kernel 2: transpose a_planar [b][cc][h][w] -> a_nhwc [b][h][w][cc].
// ---------------------------------------------------------------------------
__global__ __launch_bounds__(256) void transpose_k(const ushort* __restrict__ ap,
                                                   ushort* __restrict__ an) {
  __shared__ ushort T[64 * 128];
  const int b = blockIdx.x >> 6, h = blockIdx.x & 63;
  const int tid = threadIdx.x;
#pragma unroll
  for (int it = 0; it < 4; ++it) {
    int i = it * 256 + tid;          // 1024 16B chunks
    int cc = i >> 4, q = i & 15;
    const uint4* src = reinterpret_cast<const uint4*>(ap) +
                       ((size_t)((b * 64 + cc) * 64 + h) * 16 + q);
    *reinterpret_cast<uint4*>(&T[cc * 128 + q * 8]) = *src;
  }
  __syncthreads();
  const int p = tid >> 1, cc0 = (tid & 1) * 32;
  uint ou[16];
#pragma unroll
  for (int it = 0; it < 16; ++it) {
    uint lo = T[(cc0 + 2 * it) * 128 + p];
    uint hi = T[(cc0 + 2 * it + 1) * 128 + p];
    ou[it] = lo | (hi << 16);
  }
  uint4* dst = reinterpret_cast<uint4*>(an + ((size_t)((b * 64 + h) * 128 + p) * 64 + cc0));
#pragma unroll
  for (int r = 0; r < 4; ++r) dst[r] = make_uint4(ou[4*r], ou[4*r+1], ou[4*r+2], ou[4*r+3]);
}

// ---------------------------------------------------------------------------
// Kernel 3: weight prep -> split-precision MFMA A-fragments + biases.
//  AF[conv][tap][part][ks][mt][lane][j]; o = mt*16+(lane&15);
//  cc = ks*32 + 8*(lane>>4) + j.  part0=bf16(w), part1=bf16(w-part0).
// ---------------------------------------------------------------------------
__global__ __launch_bounds__(256) void prep_k(
    const float* __restrict__ w0r, const float* __restrict__ w0i,
    const float* __restrict__ b0r, const float* __restrict__ b0i,
    const float* __restrict__ W1r, const float* __restrict__ W1i,
    const float* __restrict__ B1r, const float* __restrict__ B1i,
    const float* __restrict__ W2r, const float* __restrict__ W2i,
    const float* __restrict__ B2r, const float* __restrict__ B2i,
    ushort* __restrict__ AF, float* __restrict__ BB) {
  const int blk = blockIdx.x, tid = threadIdx.x;
  int conv, tap, TT;
  const float *Wr, *Wi;
  if (blk == 0) { conv = 0; tap = 0; TT = 1; Wr = w0r; Wi = w0i; }
  else {
    int q = blk - 1; conv = 1 + q / 9; tap = q - (q / 9) * 9; TT = 9;
    if (conv == 1)      { Wr = W1r;        Wi = W1i; }
    else if (conv == 2) { Wr = W2r;        Wi = W2i; }
    else if (conv == 3) { Wr = W1r + 9216; Wi = W1i + 9216; }
    else                { Wr = W2r + 9216; Wi = W2i + 9216; }
  }
  ushort thi[16], tlo[16];
#pragma unroll
  for (int jj = 0; jj < 16; ++jj) {
    int e = tid * 16 + jj;
    int j = e & 7, lane_e = (e >> 3) & 63, mt = (e >> 9) & 3, ks = (e >> 11) & 1;
    int o  = mt * 16 + (lane_e & 15);
    int cc = ks * 32 + 8 * (lane_e >> 4) + j;
    int ci = cc & 31, ch = cc >> 5, on = o & 31, oh = o >> 5;
    float wr = Wr[(on * 32 + ci) * TT + tap];
    float wi = Wi[(on * 32 + ci) * TT + tap];
    float v = (oh == 0) ? (ch == 0 ? wr : -wi) : (ch == 0 ? wi : wr);
    ushort h = f2bf(v);
    thi[jj] = h;
    tlo[jj] = f2bf(v - bf2f_raw(h));
  }
  ushort* base = AF + conv * 73728 + tap * 8192 + tid * 16;
  uint4* dh = reinterpret_cast<uint4*>(base);
  uint4* dl = reinterpret_cast<uint4*>(base + 4096);
  dh[0] = *reinterpret_cast<uint4*>(&thi[0]);
  dh[1] = *reinterpret_cast<uint4*>(&thi[8]);
  dl[0] = *reinterpret_cast<uint4*>(&tlo[0]);
  dl[1] = *reinterpret_cast<uint4*>(&tlo[8]);

  if (blk == 0) {  // biases for all 5 convs
    for (int i = tid; i < 320; i += 256) {
      int c = i >> 6, o = i & 63;
      const float *br, *bi;
      if (c == 0)      { br = b0r;      bi = b0i; }
      else if (c == 1) { br = B1r;      bi = B1i; }
      else if (c == 2) { br = B2r;      bi = B2i; }
      else if (c == 3) { br = B1r + 32; bi = B1i + 32; }
      else             { br = B2r + 32; bi = B2i + 32; }
      BB[c * 64 + o] = (o < 32) ? (br[o] - bi[o]) : (br[o - 32] + bi[o - 32]);
    }
  }
}

// ---------------------------------------------------------------------------
// Kernel 4: MFMA implicit-GEMM conv, split-precision weights.
// Block = (b,h). TAPS=1|9. MODE: 0=csum init, 1=csum add, 2=store t.
// LDS: 3 rows x [wp132][cc64] bf16 XOR-swizzled; reused as fp32 [64][129].
// ---------------------------------------------------------------------------
template <int TAPS, int MODE>
__global__ __launch_bounds__(256) void conv_mfma_k(
    const ushort* __restrict__ xin, ushort* __restrict__ tout,
    const ushort* __restrict__ afrag, const float* __restrict__ bb,
    const float* __restrict__ wl0, float* __restrict__ csum, int d) {
  constexpr int ROWS = (TAPS == 1) ? 1 : 3;
  constexpr int RP = 132 * 128;              // 16896 B per staged row
  constexpr int SM = (ROWS * RP > 33024) ? ROWS * RP : 33024;
  __shared__ __align__(16) char smem[SM];
  const int b = blockIdx.x >> 6, h = blockIdx.x & 63;
  const int tid = threadIdx.x;
  const uint4 z4 = make_uint4(0u, 0u, 0u, 0u);

  // ---- stage input rows (global NHWC -> LDS swizzled) ----
  for (int r = 0; r < ROWS; ++r) {
    int hh = h + (r - ROWS / 2) * d;
    bool valid = (hh >= 0) && (hh < 64);
    int hhc = valid ? hh : 0;
    const uint4* src = reinterpret_cast<const uint4*>(xin) + (size_t)(b * 64 + hhc) * 1024;
#pragma unroll
    for (int it = 0; it < 4; ++it) {
      int i = it * 256 + tid;
      uint4 v = valid ? src[i] : z4;
      int w = i >> 3, q = i & 7;
      int wp = w + 2;
      int byt = r * RP + wp * 128 + q * 16;
      byt ^= (wp & 7) << 4;
      *reinterpret_cast<uint4*>(smem + byt) = v;
    }
    if (tid < 32) {  // zero borders wp in {0,1,130,131}
      int bi2 = tid >> 3, q = tid & 7;
      int wp = (bi2 < 2) ? bi2 : (128 + bi2);
      int byt = r * RP + wp * 128 + q * 16;
      byt ^= (wp & 7) << 4;
      *reinterpret_cast<uint4*>(smem + byt) = z4;
    }
  }
  __syncthreads();

  const int wave = tid >> 6, lane = tid & 63;
  const int mtb = (wave & 1) * 2;       // wave owns M-tiles {mtb, mtb+1}
  const int ntb = (wave >> 1) * 4;      // and N-tiles {ntb..ntb+3}
  const int l15 = lane & 15, l4 = lane >> 4;

  f32x4 acc[2][4];
#pragma unroll
  for (int mi = 0; mi < 2; ++mi)
#pragma unroll
    for (int nt = 0; nt < 4; ++nt) acc[mi][nt] = (f32x4){0.f, 0.f, 0.f, 0.f};

  const ushort* Ab = afrag + lane * 8;
  bf16x8 aC[2][2][2], aN[2][2][2];      // [part][ks][mi]
#pragma unroll
  for (int p = 0; p < 2; ++p)
#pragma unroll
    for (int ks = 0; ks < 2; ++ks)
#pragma unroll
      for (int mi = 0; mi < 2; ++mi)
        aC[p][ks][mi] = *reinterpret_cast<const bf16x8*>(
            Ab + p * 4096 + ks * 2048 + (mtb + mi) * 512);

  for (int tap = 0; tap < TAPS; ++tap) {
    if (tap + 1 < TAPS) {  // prefetch next tap's A-fragments (L2 resident)
#pragma unroll
      for (int p = 0; p < 2; ++p)
#pragma unroll
        for (int ks = 0; ks < 2; ++ks)
#pragma unroll
          for (int mi = 0; mi < 2; ++mi)
            aN[p][ks][mi] = *reinterpret_cast<const bf16x8*>(
                Ab + (tap + 1) * 8192 + p * 4096 + ks * 2048 + (mtb + mi) * 512);
    }
    const int dy = (TAPS == 1) ? 0 : (tap / 3);
    const int dx = (TAPS == 1) ? 1 : (tap - dy * 3);
    const int rowoff = dy * RP;
    const int wbase = (dx - 1) * d + 2 + l15;
#pragma unroll
    for (int ks = 0; ks < 2; ++ks) {
      bf16x8 bv[4];
#pragma unroll
      for (int nt = 0; nt < 4; ++nt) {
        int wp = (ntb + nt) * 16 + wbase;
        int byt = rowoff + wp * 128 + ks * 64 + l4 * 16;
        byt ^= (wp & 7) << 4;
        bv[nt] = *reinterpret_cast<const bf16x8*>(smem + byt);
      }
      // hi part for all 8 acc, then lo part (8-deep reuse distance)
#pragma unroll
      for (int nt = 0; nt < 4; ++nt) {
        acc[0][nt] = __builtin_amdgcn_mfma_f32_16x16x32_bf16(aC[0][ks][0], bv[nt], acc[0][nt], 0, 0, 0);
        acc[1][nt] = __builtin_amdgcn_mfma_f32_16x16x32_bf16(aC[0][ks][1], bv[nt], acc[1][nt], 0, 0, 0);
      }
#pragma unroll
      for (int nt = 0; nt < 4; ++nt) {
        acc[0][nt] = __builtin_amdgcn_mfma_f32_16x16x32_bf16(aC[1][ks][0], bv[nt], acc[0][nt], 0, 0, 0);
        acc[1][nt] = __builtin_amdgcn_mfma_f32_16x16x32_bf16(aC[1][ks][1], bv[nt], acc[1][nt], 0, 0, 0);
      }
    }
#pragma unroll
    for (int p = 0; p < 2; ++p)
#pragma unroll
      for (int ks = 0; ks < 2; ++ks)
#pragma unroll
        for (int mi = 0; mi < 2; ++mi) aC[p][ks][mi] = aN[p][ks][mi];
  }

  // ---- bounce acc through LDS (fp32 [64][129]) for coalesced writeout ----
  __syncthreads();
  float* L = reinterpret_cast<float*>(smem);
#pragma unroll
  for (int mi = 0; mi < 2; ++mi) {
    int o0 = (mtb + mi) * 16 + l4 * 4;
#pragma unroll
    for (int r = 0; r < 4; ++r) {
      float bv = bb[o0 + r];
#pragma unroll
      for (int nt = 0; nt < 4; ++nt) {
        int w = (ntb + nt) * 16 + l15;
        L[(o0 + r) * 129 + w] = acc[mi][nt][r] + bv;
      }
    }
  }
  __syncthreads();

  if constexpr (MODE == 2) {
    // store t NHWC bf16; zero pad w>=121
    const int p = tid >> 1, cc0 = (tid & 1) * 32;
    const bool val = (p < 121);
    uint ou[16];
#pragma unroll
    for (int it = 0; it < 16; ++it) {
      float v0 = val ? L[(cc0 + 2 * it) * 129 + p] : 0.f;
      float v1 = val ? L[(cc0 + 2 * it + 1) * 129 + p] : 0.f;
      ou[it] = (uint)f2bf(v0) | ((uint)f2bf(v1) << 16);
    }
    uint4* dst = reinterpret_cast<uint4*>(tout + ((size_t)((b * 64 + h) * 128 + p) * 64 + cc0));
#pragma unroll
    for (int r = 0; r < 4; ++r) dst[r] = make_uint4(ou[4*r], ou[4*r+1], ou[4*r+2], ou[4*r+3]);
  } else {
    const float w00 = wl0[0], w01 = wl0[1];
    const int n = tid >> 3, w0 = (tid & 7) * 16;
    float* crow = csum + ((size_t)(b * 32 + n) * 64 + h) * 128;
#pragma unroll
    for (int j = 0; j < 16; ++j) {
      int w = w0 + j;
      if (w < 121) {
        float rr = L[n * 129 + w], im = L[(n + 32) * 129 + w];
        float v = (fmaxf(rr, 0.f) * w00 + fmaxf(im, 0.f) * w01) * (1.f / 3.f);
        if constexpr (MODE == 1) v += crow[w];
        crow[w] = v;
      }
    }
  }
}

// ---------------------------------------------------------------------------
// Kernel 5: epilogue. h[k] = mean_f(csum) + b_l0 ; y = h @ w_l2^T + b_l2
// ---------------------------------------------------------------------------
__global__ __launch_bounds__(256) void epi_k(const float* __restrict__ csum,
    const float* __restrict__ bl0, const float* __restrict__ wl2,
    const float* __restrict__ bl2, float* __restrict__ out) {
  const int b = blockIdx.x >> 5, n = blockIdx.x & 31;
  __shared__ float sh[121];
  const int tid = threadIdx.x;
  const float* base = csum + ((size_t)(b * 32 + n) * 64) * 128;
  for (int k = tid; k < 121; k += 256) {
    float s = 0.f;
#pragma unroll 8
    for (int f = 0; f < 64; ++f) s += base[f * 128 + k];
    sh[k] = s * (1.f / 64.f) + bl0[0];
  }
  __syncthreads();
  for (int t = tid; t < 480; t += 256) {
    float acc = bl2[t];
    const float* wrow = wl2 + t * 121;
#pragma unroll 8
    for (int k = 0; k < 121; ++k) acc = fmaf(sh[k], wrow[k], acc);
    out[(b * 480 + t) * 32 + n] = acc;
  }
}

// ---------------------------------------------------------------------------
extern "C" void kernel_launch(void* const* d_in, const int* in_sizes, int n_in,
                              void* d_out, int out_size, void* d_ws, size_t ws_size,
                              hipStream_t stream) {
  const float* x   = (const float*)d_in[0];
  const float* w0r = (const float*)d_in[1];
  const float* w0i = (const float*)d_in[2];
  const float* b0r = (const float*)d_in[3];
  const float* b0i = (const float*)d_in[4];
  const float* W1r = (const float*)d_in[5];
  const float* W1i = (const float*)d_in[6];
  const float* B1r = (const float*)d_in[7];
  const float* B1i = (const float*)d_in[8];
  const float* W2r = (const float*)d_in[9];
  const float* W2i = (const float*)d_in[10];
  const float* B2r = (const float*)d_in[11];
  const float* B2i = (const float*)d_in[12];
  const float* wl0 = (const float*)d_in[13];
  const float* bl0 = (const float*)d_in[14];
  const float* wl2 = (const float*)d_in[15];
  const float* bl2 = (const float*)d_in[16];

  char* ws = (char*)d_ws;
  const size_t MB64 = (size_t)64 << 20;
  __hip_bfloat16* ap = (__hip_bfloat16*)ws;          // a_planar (dead after transpose)
  ushort* AF   = (ushort*)ws;                        // weight frags (overlay)
  float*  BB   = (float*)(ws + ((size_t)4 << 20));   // biases (overlay)
  ushort* an   = (ushort*)(ws + MB64);               // a_nhwc
  ushort* tn   = (ushort*)(ws + 2 * MB64);           // t_nhwc
  float*  csum = (float*)(ws + 3 * MB64);
  float*  out  = (float*)d_out;

  hipLaunchKernelGGL(stft_qk_a_k, dim3(2048), dim3(512), 0, stream, x, ap);
  hipLaunchKernelGGL(transpose_k, dim3(4096), dim3(256), 0, stream, (const ushort*)ap, an);
  hipLaunchKernelGGL(prep_k, dim3(37), dim3(256), 0, stream,
                     w0r, w0i, b0r, b0i, W1r, W1i, B1r, B1i, W2r, W2i, B2r, B2i, AF, BB);
  // conv0 (1x1) -> csum init
  hipLaunchKernelGGL((conv_mfma_k<1, 0>), dim3(4096), dim3(256), 0, stream,
                     an, (ushort*)nullptr, AF, BB, wl0, csum, 1);
  // pair k=1 (dilation 1)
  hipLaunchKernelGGL((conv_mfma_k<9, 2>), dim3(4096), dim3(256), 0, stream,
                     an, tn, AF + 1 * 73728, BB + 64, wl0, csum, 1);
  hipLaunchKernelGGL((conv_mfma_k<9, 1>), dim3(4096), dim3(256), 0, stream,
                     tn, (ushort*)nullptr, AF + 2 * 73728, BB + 128, wl0, csum, 1);
  // pair k=2 (dilation 2)
  hipLaunchKernelGGL((conv_mfma_k<9, 2>), dim3(4096), dim3(256), 0, stream,
                     an, tn, AF + 3 * 73728, BB + 192, wl0, csum, 2);
  hipLaunchKernelGGL((conv_mfma_k<9, 1>), dim3(4096), dim3(256), 0, stream,
                     tn, (ushort*)nullptr, AF + 4 * 73728, BB + 256, wl0, csum, 2);
  hipLaunchKernelGGL(epi_k, dim3(2048), dim3(256), 0, stream, csum, bl0, wl2, bl2, out);
}

// Round 4
// 743.694 us; speedup vs baseline: 7.4150x; 1.4222x over previous
//
#include <hip/hip_runtime.h>
#include <hip/hip_bf16.h>

// ---------------------------------------------------------------------------
// Workspace layout (256 MiB):
//  [0,64MB)    : a_planar [b][cc64][f64][w128] bf16
//  [64,128MB)  : a_nhwc   [b][h64][w128][cc64] bf16
//  [128,192MB) : t_nhwc   [b][h64][w128][cc64] bf16
//  [192,256MB) : csum     [b][n32][h64][w121]  fp32  (60.5MB)
//                tail: AF (conv weight frags hi+lo, 720KB), WF (DFT matrix
//                frags hi+lo, 32KB), BB (real-ified biases)
//
// Real-ified complex conv: channels cc<32 = real, cc>=32 = imag.
// Wbig[o][cc]: o<32 (real out): [wr | -wi]; o>=32 (imag out): [wi | wr].
// All MFMA weights split-precision: part0 = bf16(w), part1 = bf16(w-part0).
// AF layout: [conv5][tap9][part2][ks2][mt4][lane64][j8] bf16.
// WF layout: [cs2][part2][ks2][mt4][lane64][j8] bf16 (cs0 = win*cos/8,
//            cs1 = -win*sin/8 baked; A-frag: f=mt*16+(l&15), t=ks*32+(l>>4)*8+j)
// ---------------------------------------------------------------------------

typedef __attribute__((ext_vector_type(8))) short bf16x8;
typedef __attribute__((ext_vector_type(4))) short bf16x4;
typedef __attribute__((ext_vector_type(4))) float f32x4;

__device__ __forceinline__ ushort f2bf(float v) {
  __hip_bfloat16 h = __float2bfloat16(v);
  return *reinterpret_cast<ushort*>(&h);
}
__device__ __forceinline__ float bf2f_raw(ushort u) {
  union { uint i; float f; } c; c.i = ((uint)u) << 16; return c.f;
}
__device__ __forceinline__ void split_bf(float v, ushort& h, ushort& l) {
  h = f2bf(v); l = f2bf(v - bf2f_raw(h));
}
__device__ __forceinline__ bf16x8 mk8(bf16x4 a, bf16x4 b) {
  bf16x8 r;
  r[0]=a[0]; r[1]=a[1]; r[2]=a[2]; r[3]=a[3];
  r[4]=b[0]; r[5]=b[1]; r[6]=b[2]; r[7]=b[3];
  return r;
}

#define MFMA16(A,B,C) __builtin_amdgcn_mfma_f32_16x16x32_bf16(A, B, C, 0, 0, 0)
// split-precision complex of one real product X*Y: Xh*Yh + Xl*Yh + Xh*Yl
#define SPMACC(acc, Ah, Al, Bh, Bl)      \
  acc = MFMA16(Ah, Bh, acc);             \
  acc = MFMA16(Al, Bh, acc);             \
  acc = MFMA16(Ah, Bl, acc);

// ---------------------------------------------------------------------------
// Kernel 1: fused STFT + QK^T + sigmoid + A, all via MFMA. Block = (b,n).
// LDS map (bytes):
//   [0,64K)      s: s_rh@0, s_rl@16K, s_ih@32K, s_il@48K   [64 f][128 k] swz
//                  (aliased in ph2+ by Q: qrh@0, qrl@8K, qih@16K, qil@24K
//                   [64 f][64 g] swz; aliased in epilogue by bounce planes)
//   [64K,128K)   sT: tr_h@64K, tr_l@80K, ti_h@96K, ti_l@112K [128 k][64 f] swz
//   [128K,+2304) xp_h[576], xp_l[576] bf16
// ---------------------------------------------------------------------------
__global__ __launch_bounds__(512) void stft_mfma_k(const float* __restrict__ x,
                                                   const ushort* __restrict__ WF,
                                                   ushort* __restrict__ ap) {
  __shared__ __align__(16) char smem[133376];
  const int bid = blockIdx.x;
  const int b = bid >> 5, n = bid & 31;
  const int tid = threadIdx.x;
  ushort* xph = reinterpret_cast<ushort*>(smem + 131072);
  ushort* xpl = xph + 576;

  // ---- phase 0: reflect-padded signal, split hi/lo ----
  for (int i = tid; i < 576; i += 512) {
    float v = 0.f;
    if (i < 544) {
      int p = i - 32;
      if (p < 0) p = -p;
      if (p >= 480) p = 958 - p;
      v = x[(b * 480 + p) * 32 + n];
    }
    ushort h, l; split_bf(v, h, l);
    xph[i] = h; xpl[i] = l;
  }
  __syncthreads();

  const int wv = tid >> 6, lane = tid & 63;
  const int mt = wv >> 1, nth = wv & 1;
  const int l15 = lane & 15, l4 = lane >> 4;

  // ---- phase 1: DFT  s[f][k] = W'[f][t] @ frames[t][k], frames[t][k]=xp[4k+t]
  bf16x8 WA[2][2][2];  // [cs][part][ks]
#pragma unroll
  for (int cs = 0; cs < 2; ++cs)
#pragma unroll
    for (int part = 0; part < 2; ++part)
#pragma unroll
      for (int ks = 0; ks < 2; ++ks)
        WA[cs][part][ks] = *reinterpret_cast<const bf16x8*>(
            WF + (((cs * 2 + part) * 2 + ks) * 4 + mt) * 512 + lane * 8);

  f32x4 acc1[2][4];
#pragma unroll
  for (int cs = 0; cs < 2; ++cs)
#pragma unroll
    for (int nt = 0; nt < 4; ++nt) acc1[cs][nt] = (f32x4){0.f, 0.f, 0.f, 0.f};

#pragma unroll
  for (int ks = 0; ks < 2; ++ks) {
    bf16x8 bh[4], bl[4];
#pragma unroll
    for (int nt = 0; nt < 4; ++nt) {
      int n_ = ((nth * 4 + nt) * 16) + l15;      // frame index (N dim)
      int e = n_ * 4 + ks * 32 + l4 * 8;
      bf16x4 h0 = *reinterpret_cast<const bf16x4*>(xph + e);
      bf16x4 h1 = *reinterpret_cast<const bf16x4*>(xph + e + 4);
      bf16x4 l0 = *reinterpret_cast<const bf16x4*>(xpl + e);
      bf16x4 l1 = *reinterpret_cast<const bf16x4*>(xpl + e + 4);
      bh[nt] = mk8(h0, h1); bl[nt] = mk8(l0, l1);
    }
#pragma unroll
    for (int cs = 0; cs < 2; ++cs)
#pragma unroll
      for (int nt = 0; nt < 4; ++nt) {
        SPMACC(acc1[cs][nt], WA[cs][0][ks], WA[cs][1][ks], bh[nt], bl[nt]);
      }
  }

  // write s[f][k] (row 256B, swz ^(f&7)<<4) and sT[k][f] (row 128B, ^(k&7)<<4)
#pragma unroll
  for (int cs = 0; cs < 2; ++cs)
#pragma unroll
    for (int nt = 0; nt < 4; ++nt) {
      int k = (nth * 4 + nt) * 16 + l15;
      bool kv = (k < 121);
#pragma unroll
      for (int r = 0; r < 4; ++r) {
        int f = mt * 16 + l4 * 4 + r;
        float v = kv ? acc1[cs][nt][r] : 0.f;
        ushort h, l; split_bf(v, h, l);
        int ba = (f << 8) + (k << 1); ba ^= (f & 7) << 4;
        *reinterpret_cast<ushort*>(smem + cs * 32768 + ba) = h;
        *reinterpret_cast<ushort*>(smem + cs * 32768 + 16384 + ba) = l;
        int bt = (k << 7) + (f << 1); bt ^= (k & 7) << 4;
        *reinterpret_cast<ushort*>(smem + 65536 + cs * 32768 + bt) = h;
        *reinterpret_cast<ushort*>(smem + 65536 + cs * 32768 + 16384 + bt) = l;
      }
    }
  __syncthreads();

  // ---- phase 2: QK^T + sigmoid.  qr = sr@sr^T - si@si^T ; qi = sr@si^T + si@sr^T
  f32x4 acc2[2][4];  // [nt][rr, ii, ri, ir]
#pragma unroll
  for (int nt = 0; nt < 2; ++nt)
#pragma unroll
    for (int c = 0; c < 4; ++c) acc2[nt][c] = (f32x4){0.f, 0.f, 0.f, 0.f};

#pragma unroll
  for (int ks = 0; ks < 4; ++ks) {
    bf16x8 A_[2][2];  // [comp][part], rows f = mt*16+l15
#pragma unroll
    for (int comp = 0; comp < 2; ++comp)
#pragma unroll
      for (int part = 0; part < 2; ++part) {
        int f = mt * 16 + l15;
        int ba = (f << 8) + ((ks * 32 + l4 * 8) << 1); ba ^= (f & 7) << 4;
        A_[comp][part] = *reinterpret_cast<const bf16x8*>(smem + comp * 32768 + part * 16384 + ba);
      }
    bf16x8 B_[2][2][2];  // [comp][part][nt], rows g
#pragma unroll
    for (int comp = 0; comp < 2; ++comp)
#pragma unroll
      for (int part = 0; part < 2; ++part)
#pragma unroll
        for (int nt = 0; nt < 2; ++nt) {
          int g = (nth * 2 + nt) * 16 + l15;
          int ba = (g << 8) + ((ks * 32 + l4 * 8) << 1); ba ^= (g & 7) << 4;
          B_[comp][part][nt] = *reinterpret_cast<const bf16x8*>(smem + comp * 32768 + part * 16384 + ba);
        }
#pragma unroll
    for (int nt = 0; nt < 2; ++nt) {
      SPMACC(acc2[nt][0], A_[0][0], A_[0][1], B_[0][0][nt], B_[0][1][nt]);  // rr
      SPMACC(acc2[nt][1], A_[1][0], A_[1][1], B_[1][0][nt], B_[1][1][nt]);  // ii
      SPMACC(acc2[nt][2], A_[0][0], A_[0][1], B_[1][0][nt], B_[1][1][nt]);  // ri
      SPMACC(acc2[nt][3], A_[1][0], A_[1][1], B_[0][0][nt], B_[0][1][nt]);  // ir
    }
  }
  __syncthreads();  // all s reads done before Q overwrites s region

  // sigmoid + split -> Q planes: qrh@0 qrl@8K qih@16K qil@24K, [64 f][64 g] swz(f)
#pragma unroll
  for (int nt = 0; nt < 2; ++nt) {
    int g = (nth * 2 + nt) * 16 + l15;
#pragma unroll
    for (int r = 0; r < 4; ++r) {
      int f = mt * 16 + l4 * 4 + r;
      float qr = acc2[nt][0][r] - acc2[nt][1][r];
      float qi = acc2[nt][2][r] + acc2[nt][3][r];
      float vr = 1.f / (1.f + __expf(-qr));
      float vi = 1.f / (1.f + __expf(-qi));
      int ba = (f << 7) + (g << 1); ba ^= (f & 7) << 4;
      ushort h, l;
      split_bf(vr, h, l);
      *reinterpret_cast<ushort*>(smem + ba) = h;
      *reinterpret_cast<ushort*>(smem + 8192 + ba) = l;
      split_bf(vi, h, l);
      *reinterpret_cast<ushort*>(smem + 16384 + ba) = h;
      *reinterpret_cast<ushort*>(smem + 24576 + ba) = l;
    }
  }
  __syncthreads();

  // ---- phase 3: A = Q @ S.  ar = Qr@sTr - Qi@sTi ; ai = Qr@sTi + Qi@sTr
  f32x4 acc3[4][3];  // [nt][arp, arm, ai]
#pragma unroll
  for (int nt = 0; nt < 4; ++nt)
#pragma unroll
    for (int c = 0; c < 3; ++c) acc3[nt][c] = (f32x4){0.f, 0.f, 0.f, 0.f};

#pragma unroll
  for (int ks = 0; ks < 2; ++ks) {
    bf16x8 QA[2][2];  // [comp][part], rows f
#pragma unroll
    for (int comp = 0; comp < 2; ++comp)
#pragma unroll
      for (int part = 0; part < 2; ++part) {
        int f = mt * 16 + l15;
        int ba = (f << 7) + ((ks * 32 + l4 * 8) << 1); ba ^= (f & 7) << 4;
        QA[comp][part] = *reinterpret_cast<const bf16x8*>(smem + comp * 16384 + part * 8192 + ba);
      }
#pragma unroll
    for (int nt = 0; nt < 4; ++nt) {
      int k = (nth * 4 + nt) * 16 + l15;
      int bq = (k << 7) + ((ks * 32 + l4 * 8) << 1); bq ^= (k & 7) << 4;
      bf16x8 Srh = *reinterpret_cast<const bf16x8*>(smem + 65536 + bq);
      bf16x8 Srl = *reinterpret_cast<const bf16x8*>(smem + 81920 + bq);
      bf16x8 Sih = *reinterpret_cast<const bf16x8*>(smem + 98304 + bq);
      bf16x8 Sil = *reinterpret_cast<const bf16x8*>(smem + 114688 + bq);
      SPMACC(acc3[nt][0], QA[0][0], QA[0][1], Srh, Srl);  // Qr*sTr
      SPMACC(acc3[nt][1], QA[1][0], QA[1][1], Sih, Sil);  // Qi*sTi
      SPMACC(acc3[nt][2], QA[0][0], QA[0][1], Sih, Sil);  // Qr*sTi
      SPMACC(acc3[nt][2], QA[1][0], QA[1][1], Srh, Srl);  // Qi*sTr
    }
  }
  __syncthreads();  // all Q/sT reads done before bounce overwrites

  // bounce: plane ar @0, ai @16K : [64 f][128 k] bf16, swz ^(f&7)<<4
#pragma unroll
  for (int nt = 0; nt < 4; ++nt) {
    int k = (nth * 4 + nt) * 16 + l15;
#pragma unroll
    for (int r = 0; r < 4; ++r) {
      int f = mt * 16 + l4 * 4 + r;
      float ar = acc3[nt][0][r] - acc3[nt][1][r];
      float ai = acc3[nt][2][r];
      int ba = (f << 8) + (k << 1); ba ^= (f & 7) << 4;
      *reinterpret_cast<ushort*>(smem + ba) = f2bf(ar);
      *reinterpret_cast<ushort*>(smem + 16384 + ba) = f2bf(ai);
    }
  }
  __syncthreads();

  uint4* dst = reinterpret_cast<uint4*>(ap);
  for (int i = tid; i < 2048; i += 512) {
    int comp = i >> 10, rem = i & 1023;
    int f = rem >> 4, q = rem & 15;
    uint4 v = *reinterpret_cast<const uint4*>(
        smem + comp * 16384 + (f << 8) + ((q ^ (f & 7)) << 4));
    dst[((size_t)(b * 64 + n + 32 * comp) * 64) * 16 + rem] = v;
  }
}

// ---------------------------------------------------------------------------
// Kernel 2: transpose a_planar [b][cc][h][w] -> a_nhwc [b][h][w][cc].
// ---------------------------------------------------------------------------
__global__ __launch_bounds__(256) void transpose_k(const ushort* __restrict__ ap,
                                                   ushort* __restrict__ an) {
  __shared__ ushort T[64 * 128];
  const int b = blockIdx.x >> 6, h = blockIdx.x & 63;
  const int tid = threadIdx.x;
#pragma unroll
  for (int it = 0; it < 4; ++it) {
    int i = it * 256 + tid;          // 1024 16B chunks
    int cc = i >> 4, q = i & 15;
    const uint4* src = reinterpret_cast<const uint4*>(ap) +
                       ((size_t)((b * 64 + cc) * 64 + h) * 16 + q);
    *reinterpret_cast<uint4*>(&T[cc * 128 + q * 8]) = *src;
  }
  __syncthreads();
  const int p = tid >> 1, cc0 = (tid & 1) * 32;
  uint ou[16];
#pragma unroll
  for (int it = 0; it < 16; ++it) {
    uint lo = T[(cc0 + 2 * it) * 128 + p];
    uint hi = T[(cc0 + 2 * it + 1) * 128 + p];
    ou[it] = lo | (hi << 16);
  }
  uint4* dst = reinterpret_cast<uint4*>(an + ((size_t)((b * 64 + h) * 128 + p) * 64 + cc0));
#pragma unroll
  for (int r = 0; r < 4; ++r) dst[r] = make_uint4(ou[4*r], ou[4*r+1], ou[4*r+2], ou[4*r+3]);
}

// ---------------------------------------------------------------------------
// Kernel 3: prep. blk<37: conv weight frags (split hi/lo) + biases.
//           blk==37: DFT matrix frags WF (win & 1/8 baked in, split hi/lo).
// ---------------------------------------------------------------------------
__global__ __launch_bounds__(256) void prep_k(
    const float* __restrict__ w0r, const float* __restrict__ w0i,
    const float* __restrict__ b0r, const float* __restrict__ b0i,
    const float* __restrict__ W1r, const float* __restrict__ W1i,
    const float* __restrict__ B1r, const float* __restrict__ B1i,
    const float* __restrict__ W2r, const float* __restrict__ W2i,
    const float* __restrict__ B2r, const float* __restrict__ B2i,
    ushort* __restrict__ AF, ushort* __restrict__ WF, float* __restrict__ BB) {
  const int blk = blockIdx.x, tid = threadIdx.x;
  const float PI32 = 0.0981747704246810387f;  // pi/32

  if (blk == 37) {  // DFT matrices: cs0 = win*cos/8, cs1 = -win*sin/8
    for (int i = tid; i < 16384; i += 256) {
      int j = i & 7, ln = (i >> 3) & 63, mt = (i >> 9) & 3, ks = (i >> 11) & 1;
      int part = (i >> 12) & 1, cs = (i >> 13) & 1;
      int f = mt * 16 + (ln & 15);
      int t = ks * 32 + (ln >> 4) * 8 + j;
      float win = 0.5f * (1.0f - __cosf(PI32 * (float)t));
      int m = (f * t) & 63;
      float sv, cv;
      __sincosf(PI32 * (float)m, &sv, &cv);
      float val = (cs == 0) ? (win * cv * 0.125f) : (-win * sv * 0.125f);
      ushort h = f2bf(val);
      WF[i] = part ? f2bf(val - bf2f_raw(h)) : h;
    }
    return;
  }

  int conv, tap, TT;
  const float *Wr, *Wi;
  if (blk == 0) { conv = 0; tap = 0; TT = 1; Wr = w0r; Wi = w0i; }
  else {
    int q = blk - 1; conv = 1 + q / 9; tap = q - (q / 9) * 9; TT = 9;
    if (conv == 1)      { Wr = W1r;        Wi = W1i; }
    else if (conv == 2) { Wr = W2r;        Wi = W2i; }
    else if (conv == 3) { Wr = W1r + 9216; Wi = W1i + 9216; }
    else                { Wr = W2r + 9216; Wi = W2i + 9216; }
  }
  ushort thi[16], tlo[16];
#pragma unroll
  for (int jj = 0; jj < 16; ++jj) {
    int e = tid * 16 + jj;
    int j = e & 7, lane_e = (e >> 3) & 63, mt = (e >> 9) & 3, ks = (e >> 11) & 1;
    int o  = mt * 16 + (lane_e & 15);
    int cc = ks * 32 + 8 * (lane_e >> 4) + j;
    int ci = cc & 31, ch = cc >> 5, on = o & 31, oh = o >> 5;
    float wr = Wr[(on * 32 + ci) * TT + tap];
    float wi = Wi[(on * 32 + ci) * TT + tap];
    float v = (oh == 0) ? (ch == 0 ? wr : -wi) : (ch == 0 ? wi : wr);
    ushort h = f2bf(v);
    thi[jj] = h;
    tlo[jj] = f2bf(v - bf2f_raw(h));
  }
  ushort* base = AF + conv * 73728 + tap * 8192 + tid * 16;
  uint4* dh = reinterpret_cast<uint4*>(base);
  uint4* dl = reinterpret_cast<uint4*>(base + 4096);
  dh[0] = *reinterpret_cast<uint4*>(&thi[0]);
  dh[1] = *reinterpret_cast<uint4*>(&thi[8]);
  dl[0] = *reinterpret_cast<uint4*>(&tlo[0]);
  dl[1] = *reinterpret_cast<uint4*>(&tlo[8]);

  if (blk == 0) {  // biases for all 5 convs
    for (int i = tid; i < 320; i += 256) {
      int c = i >> 6, o = i & 63;
      const float *br, *bi;
      if (c == 0)      { br = b0r;      bi = b0i; }
      else if (c == 1) { br = B1r;      bi = B1i; }
      else if (c == 2) { br = B2r;      bi = B2i; }
      else if (c == 3) { br = B1r + 32; bi = B1i + 32; }
      else             { br = B2r + 32; bi = B2i + 32; }
      BB[c * 64 + o] = (o < 32) ? (br[o] - bi[o]) : (br[o - 32] + bi[o - 32]);
    }
  }
}

// ---------------------------------------------------------------------------
// Kernel 4: MFMA implicit-GEMM conv, split-precision weights.
// Block = (b,h) via XCD-aware swizzle (consecutive h co-resident per XCD for
// L2 reuse of the 3 staged rows). TAPS=1|9. MODE: 0=csum init, 1=add, 2=store t.
// ---------------------------------------------------------------------------
template <int TAPS, int MODE>
__global__ __launch_bounds__(256) void conv_mfma_k(
    const ushort* __restrict__ xin, ushort* __restrict__ tout,
    const ushort* __restrict__ afrag, const float* __restrict__ bb,
    const float* __restrict__ wl0, float* __restrict__ csum, int d) {
  constexpr int ROWS = (TAPS == 1) ? 1 : 3;
  constexpr int RP = 132 * 128;              // 16896 B per staged row
  constexpr int SM = (ROWS * RP > 33024) ? ROWS * RP : 33024;
  __shared__ __align__(16) char smem[SM];
  // XCD swizzle: 4096 blocks, 8 XCDs -> each XCD gets contiguous 512 (b,h)
  const int wg = ((blockIdx.x & 7) << 9) | (blockIdx.x >> 3);
  const int b = wg >> 6, h = wg & 63;
  const int tid = threadIdx.x;
  const uint4 z4 = make_uint4(0u, 0u, 0u, 0u);

  for (int r = 0; r < ROWS; ++r) {
    int hh = h + (r - ROWS / 2) * d;
    bool valid = (hh >= 0) && (hh < 64);
    int hhc = valid ? hh : 0;
    const uint4* src = reinterpret_cast<const uint4*>(xin) + (size_t)(b * 64 + hhc) * 1024;
#pragma unroll
    for (int it = 0; it < 4; ++it) {
      int i = it * 256 + tid;
      uint4 v = valid ? src[i] : z4;
      int w = i >> 3, q = i & 7;
      int wp = w + 2;
      int byt = r * RP + wp * 128 + q * 16;
      byt ^= (wp & 7) << 4;
      *reinterpret_cast<uint4*>(smem + byt) = v;
    }
    if (tid < 32) {  // zero borders wp in {0,1,130,131}
      int bi2 = tid >> 3, q = tid & 7;
      int wp = (bi2 < 2) ? bi2 : (128 + bi2);
      int byt = r * RP + wp * 128 + q * 16;
      byt ^= (wp & 7) << 4;
      *reinterpret_cast<uint4*>(smem + byt) = z4;
    }
  }
  __syncthreads();

  const int wave = tid >> 6, lane = tid & 63;
  const int mtb = (wave & 1) * 2;
  const int ntb = (wave >> 1) * 4;
  const int l15 = lane & 15, l4 = lane >> 4;

  f32x4 acc[2][4];
#pragma unroll
  for (int mi = 0; mi < 2; ++mi)
#pragma unroll
    for (int nt = 0; nt < 4; ++nt) acc[mi][nt] = (f32x4){0.f, 0.f, 0.f, 0.f};

  const ushort* Ab = afrag + lane * 8;
  bf16x8 aC[2][2][2], aN[2][2][2];      // [part][ks][mi]
#pragma unroll
  for (int p = 0; p < 2; ++p)
#pragma unroll
    for (int ks = 0; ks < 2; ++ks)
#pragma unroll
      for (int mi = 0; mi < 2; ++mi)
        aC[p][ks][mi] = *reinterpret_cast<const bf16x8*>(
            Ab + p * 4096 + ks * 2048 + (mtb + mi) * 512);

  for (int tap = 0; tap < TAPS; ++tap) {
    if (tap + 1 < TAPS) {
#pragma unroll
      for (int p = 0; p < 2; ++p)
#pragma unroll
        for (int ks = 0; ks < 2; ++ks)
#pragma unroll
          for (int mi = 0; mi < 2; ++mi)
            aN[p][ks][mi] = *reinterpret_cast<const bf16x8*>(
                Ab + (tap + 1) * 8192 + p * 4096 + ks * 2048 + (mtb + mi) * 512);
    }
    const int dy = (TAPS == 1) ? 0 : (tap / 3);
    const int dx = (TAPS == 1) ? 1 : (tap - dy * 3);
    const int rowoff = dy * RP;
    const int wbase = (dx - 1) * d + 2 + l15;
#pragma unroll
    for (int ks = 0; ks < 2; ++ks) {
      bf16x8 bv[4];
#pragma unroll
      for (int nt = 0; nt < 4; ++nt) {
        int wp = (ntb + nt) * 16 + wbase;
        int byt = rowoff + wp * 128 + ks * 64 + l4 * 16;
        byt ^= (wp & 7) << 4;
        bv[nt] = *reinterpret_cast<const bf16x8*>(smem + byt);
      }
#pragma unroll
      for (int nt = 0; nt < 4; ++nt) {
        acc[0][nt] = MFMA16(aC[0][ks][0], bv[nt], acc[0][nt]);
        acc[1][nt] = MFMA16(aC[0][ks][1], bv[nt], acc[1][nt]);
      }
#pragma unroll
      for (int nt = 0; nt < 4; ++nt) {
        acc[0][nt] = MFMA16(aC[1][ks][0], bv[nt], acc[0][nt]);
        acc[1][nt] = MFMA16(aC[1][ks][1], bv[nt], acc[1][nt]);
      }
    }
#pragma unroll
    for (int p = 0; p < 2; ++p)
#pragma unroll
      for (int ks = 0; ks < 2; ++ks)
#pragma unroll
        for (int mi = 0; mi < 2; ++mi) aC[p][ks][mi] = aN[p][ks][mi];
  }

  __syncthreads();
  float* L = reinterpret_cast<float*>(smem);
#pragma unroll
  for (int mi = 0; mi < 2; ++mi) {
    int o0 = (mtb + mi) * 16 + l4 * 4;
#pragma unroll
    for (int r = 0; r < 4; ++r) {
      float bv = bb[o0 + r];
#pragma unroll
      for (int nt = 0; nt < 4; ++nt) {
        int w = (ntb + nt) * 16 + l15;
        L[(o0 + r) * 129 + w] = acc[mi][nt][r] + bv;
      }
    }
  }
  __syncthreads();

  if constexpr (MODE == 2) {
    const int p = tid >> 1, cc0 = (tid & 1) * 32;
    const bool val = (p < 121);
    uint ou[16];
#pragma unroll
    for (int it = 0; it < 16; ++it) {
      float v0 = val ? L[(cc0 + 2 * it) * 129 + p] : 0.f;
      float v1 = val ? L[(cc0 + 2 * it + 1) * 129 + p] : 0.f;
      ou[it] = (uint)f2bf(v0) | ((uint)f2bf(v1) << 16);
    }
    uint4* dst = reinterpret_cast<uint4*>(tout + ((size_t)((b * 64 + h) * 128 + p) * 64 + cc0));
#pragma unroll
    for (int r = 0; r < 4; ++r) dst[r] = make_uint4(ou[4*r], ou[4*r+1], ou[4*r+2], ou[4*r+3]);
  } else {
    const float w00 = wl0[0], w01 = wl0[1];
    const int n = tid >> 3, w0 = (tid & 7) * 16;
    float* crow = csum + ((size_t)(b * 32 + n) * 64 + h) * 121;
#pragma unroll
    for (int j = 0; j < 16; ++j) {
      int w = w0 + j;
      if (w < 121) {
        float rr = L[n * 129 + w], im = L[(n + 32) * 129 + w];
        float v = (fmaxf(rr, 0.f) * w00 + fmaxf(im, 0.f) * w01) * (1.f / 3.f);
        if constexpr (MODE == 1) v += crow[w];
        crow[w] = v;
      }
    }
  }
}

// ---------------------------------------------------------------------------
// Kernel 5: epilogue. h[k] = mean_f(csum) + b_l0 ; y = h @ w_l2^T + b_l2
// ---------------------------------------------------------------------------
__global__ __launch_bounds__(256) void epi_k(const float* __restrict__ csum,
    const float* __restrict__ bl0, const float* __restrict__ wl2,
    const float* __restrict__ bl2, float* __restrict__ out) {
  const int b = blockIdx.x >> 5, n = blockIdx.x & 31;
  __shared__ float sh[121];
  const int tid = threadIdx.x;
  const float* base = csum + (size_t)(b * 32 + n) * 64 * 121;
  for (int k = tid; k < 121; k += 256) {
    float s = 0.f;
#pragma unroll 8
    for (int f = 0; f < 64; ++f) s += base[f * 121 + k];
    sh[k] = s * (1.f / 64.f) + bl0[0];
  }
  __syncthreads();
  for (int t = tid; t < 480; t += 256) {
    float acc = bl2[t];
    const float* wrow = wl2 + t * 121;
#pragma unroll 8
    for (int k = 0; k < 121; ++k) acc = fmaf(sh[k], wrow[k], acc);
    out[(b * 480 + t) * 32 + n] = acc;
  }
}

// ---------------------------------------------------------------------------
extern "C" void kernel_launch(void* const* d_in, const int* in_sizes, int n_in,
                              void* d_out, int out_size, void* d_ws, size_t ws_size,
                              hipStream_t stream) {
  const float* x   = (const float*)d_in[0];
  const float* w0r = (const float*)d_in[1];
  const float* w0i = (const float*)d_in[2];
  const float* b0r = (const float*)d_in[3];
  const float* b0i = (const float*)d_in[4];
  const float* W1r = (const float*)d_in[5];
  const float* W1i = (const float*)d_in[6];
  const float* B1r = (const float*)d_in[7];
  const float* B1i = (const float*)d_in[8];
  const float* W2r = (const float*)d_in[9];
  const float* W2i = (const float*)d_in[10];
  const float* B2r = (const float*)d_in[11];
  const float* B2i = (const float*)d_in[12];
  const float* wl0 = (const float*)d_in[13];
  const float* bl0 = (const float*)d_in[14];
  const float* wl2 = (const float*)d_in[15];
  const float* bl2 = (const float*)d_in[16];

  char* ws = (char*)d_ws;
  const size_t MB64 = (size_t)64 << 20;
  ushort* ap   = (ushort*)ws;                        // a_planar
  ushort* an   = (ushort*)(ws + MB64);               // a_nhwc
  ushort* tn   = (ushort*)(ws + 2 * MB64);           // t_nhwc
  float*  csum = (float*)(ws + 3 * MB64);            // [b][32][64][121] fp32
  const size_t CSZ = (size_t)64 * 32 * 64 * 121 * 4; // 63,438,848 B
  ushort* AF   = (ushort*)(ws + 3 * MB64 + CSZ);     // 737,280 B
  ushort* WFp  = AF + 5 * 73728;                     // 32,768 B
  float*  BB   = (float*)(WFp + 16384);              // 1,280 B
  float*  out  = (float*)d_out;

  hipLaunchKernelGGL(prep_k, dim3(38), dim3(256), 0, stream,
                     w0r, w0i, b0r, b0i, W1r, W1i, B1r, B1i, W2r, W2i, B2r, B2i,
                     AF, WFp, BB);
  hipLaunchKernelGGL(stft_mfma_k, dim3(2048), dim3(512), 0, stream, x, WFp, ap);
  hipLaunchKernelGGL(transpose_k, dim3(4096), dim3(256), 0, stream, ap, an);
  // conv0 (1x1) -> csum init
  hipLaunchKernelGGL((conv_mfma_k<1, 0>), dim3(4096), dim3(256), 0, stream,
                     an, (ushort*)nullptr, AF, BB, wl0, csum, 1);
  // pair k=1 (dilation 1)
  hipLaunchKernelGGL((conv_mfma_k<9, 2>), dim3(4096), dim3(256), 0, stream,
                     an, tn, AF + 1 * 73728, BB + 64, wl0, csum, 1);
  hipLaunchKernelGGL((conv_mfma_k<9, 1>), dim3(4096), dim3(256), 0, stream,
                     tn, (ushort*)nullptr, AF + 2 * 73728, BB + 128, wl0, csum, 1);
  // pair k=2 (dilation 2)
  hipLaunchKernelGGL((conv_mfma_k<9, 2>), dim3(4096), dim3(256), 0, stream,
                     an, tn, AF + 3 * 73728, BB + 192, wl0, csum, 2);
  hipLaunchKernelGGL((conv_mfma_k<9, 1>), dim3(4096), dim3(256), 0, stream,
                     tn, (ushort*)nullptr, AF + 4 * 73728, BB + 256, wl0, csum, 2);
  hipLaunchKernelGGL(epi_k, dim3(2048), dim3(256), 0, stream, csum, bl0, wl2, bl2, out);
}